// Round 12
// baseline (131.344 us; speedup 1.0000x reference)
//
#include <hip/hip_runtime.h>
#include <hip/hip_cooperative_groups.h>
#include <hip/hip_bf16.h>
#include <stdint.h>

namespace cg = cooperative_groups;

// Problem constants (fixed shapes from setup_inputs)
constexpr int   kC       = 19;
constexpr int   kHW      = 512 * 512;      // 262144 = 2^18
constexpr int   kHWShift = 18;
constexpr int   kN       = 8 * kHW;        // 2097152 pixels
constexpr int   kIgnore  = 255;
constexpr float kThresh  = 0.7f;
constexpr int   kMinKept = 100000;

constexpr int H1_BINS = 32768;   // top-16 bits of a non-negative float
constexpr int H2_BINS = 65536;   // low-16 bits
constexpr int kOhemBlocks = 256; // cooperative grid (1 block/CU co-resident)

// ---------------------------------------------------------------------------
// K1: pred from score1. GOLDEN structure (pure load->compute->one float4
// store; holds the 19-float4 load hoist, ~4.7 TB/s). UNCHANGED since R9.
// ---------------------------------------------------------------------------
__global__ __launch_bounds__(256) void k_pred(const float* __restrict__ s1,
                                              const int* __restrict__ tgt,
                                              float* __restrict__ pred)
{
    const int i4 = blockIdx.x * blockDim.x + threadIdx.x;
    const int i  = i4 * 4;
    const int b  = i >> kHWShift;
    const int hw = i & (kHW - 1);
    const float* p1 = s1 + (size_t)b * kC * kHW + hw;

    float4 v[kC];
    #pragma unroll
    for (int c = 0; c < kC; ++c)
        v[c] = *(const float4*)(p1 + (size_t)c * kHW);   // all independent

    const int4 t4 = *(const int4*)(tgt + i);
    int tt[4] = {t4.x, t4.y, t4.z, t4.w};
    bool mk[4];
    #pragma unroll
    for (int q = 0; q < 4; ++q) {
        mk[q] = (tt[q] != kIgnore);
        tt[q] = mk[q] ? tt[q] : 0;
    }

    float sum[4] = {0.f, 0.f, 0.f, 0.f}, st[4] = {0.f, 0.f, 0.f, 0.f};
    #pragma unroll
    for (int c = 0; c < kC; ++c) {
        const float av[4] = {v[c].x, v[c].y, v[c].z, v[c].w};
        #pragma unroll
        for (int q = 0; q < 4; ++q) {
            sum[q] += __expf(av[q]);
            st[q] = (c == tt[q]) ? av[q] : st[q];
        }
    }

    float4 p4;
    p4.x = mk[0] ? (__expf(st[0]) / sum[0]) : __uint_as_float(0x7f800000u);
    p4.y = mk[1] ? (__expf(st[1]) / sum[1]) : __uint_as_float(0x7f800000u);
    p4.z = mk[2] ? (__expf(st[2]) / sum[2]) : __uint_as_float(0x7f800000u);
    p4.w = mk[3] ? (__expf(st[3]) / sum[3]) : __uint_as_float(0x7f800000u);
    *(float4*)(pred + i) = p4;
}

// ---------------------------------------------------------------------------
// K2: the ENTIRE scalar pipeline in one cooperative kernel (replaces 9
// launches; R11 showed ~12 µs of serial dispatch gaps). Phases separated by
// grid.sync(). Skip path (threshold=0.7, the common case): one 8.4 MB stats
// pass computes counts AND the speculative num/den at 0.7 -> ohem ready
// after 2 grid syncs. Hist path (general inputs) fully preserved in-kernel.
// ---------------------------------------------------------------------------
__global__ __launch_bounds__(256) void k_ohem(const float* __restrict__ pred,
                                              unsigned int* __restrict__ pcnt,
                                              unsigned int* __restrict__ pcle,
                                              unsigned int* __restrict__ pden,
                                              float*        __restrict__ pnum,
                                              unsigned int* __restrict__ sel,
                                              float*        __restrict__ thr,
                                              float*        __restrict__ ohem_half,
                                              unsigned int* __restrict__ hist1,
                                              unsigned int* __restrict__ hist2)
{
    cg::grid_group grid = cg::this_grid();
    const int t       = threadIdx.x;
    const int bid     = blockIdx.x;
    const int gtid    = bid * 256 + t;
    const int gstride = kOhemBlocks * 256;   // 65536
    const float inf   = __uint_as_float(0x7f800000u);

    __shared__ unsigned int h[H1_BINS / 2];            // 64 KB (hist1 phase)
    __shared__ unsigned int su[256], sv[256], sw[256];
    __shared__ float sf[256];

    // ---- P0: stats pass: cnt(!=inf), cle(<=0.7), den7(<0.7), num7 ----
    {
        int cnt = 0, cle = 0, den = 0; float num = 0.f;
        for (int i4 = gtid; i4 < kN / 4; i4 += gstride) {
            const float4 p4 = *(const float4*)(pred + i4 * 4);
            const float p[4] = {p4.x, p4.y, p4.z, p4.w};
            #pragma unroll
            for (int q = 0; q < 4; ++q) {
                cnt += (int)(p[q] != inf);
                cle += (int)(p[q] <= kThresh);
                if (p[q] < kThresh) { den += 1; num += -__logf(p[q]); }
            }
        }
        su[t] = (unsigned)cnt; sv[t] = (unsigned)cle;
        sw[t] = (unsigned)den; sf[t] = num;
        __syncthreads();
        for (int o = 128; o > 0; o >>= 1) {
            if (t < o) { su[t]+=su[t+o]; sv[t]+=sv[t+o]; sw[t]+=sw[t+o]; sf[t]+=sf[t+o]; }
            __syncthreads();
        }
        if (t == 0) { pcnt[bid]=su[0]; pcle[bid]=sv[0]; pden[bid]=sw[0]; pnum[bid]=sf[0]; }
    }
    grid.sync();

    // ---- P1: decide (block 0). On skip, ohem is final here. ----
    if (bid == 0) {
        su[t]=pcnt[t]; sv[t]=pcle[t]; sw[t]=pden[t]; sf[t]=pnum[t];
        __syncthreads();
        for (int o = 128; o > 0; o >>= 1) {
            if (t < o) { su[t]+=su[t+o]; sv[t]+=sv[t+o]; sw[t]+=sw[t+o]; sf[t]+=sf[t+o]; }
            __syncthreads();
        }
        if (t == 0) {
            const unsigned n_valid = su[0], cnt_le = sv[0];
            long long idx = (long long)n_valid - 1;
            if (idx > kMinKept) idx = kMinKept;
            if (idx < 0) idx = 0;
            const unsigned uidx = (unsigned)idx;
            sel[3] = uidx;
            const bool skip = (cnt_le >= uidx + 1);   // sorted[idx] <= 0.7
            sel[2] = skip ? 1u : 0u;
            *thr = kThresh;
            if (skip) *ohem_half = 0.5f * (sf[0] / (float)sw[0]);
        }
    }
    grid.sync();
    if (sel[2]) return;                                // common case: done

    // ---- P3: zero global hists ----
    for (int j = gtid; j < H1_BINS + H2_BINS; j += gstride) {
        if (j < H1_BINS) hist1[j] = 0u; else hist2[j - H1_BINS] = 0u;
    }
    grid.sync();

    // ---- P4: hist1 of top-16 bits (LDS-privatized u16 pairs) ----
    for (int j = t; j < H1_BINS / 2; j += 256) h[j] = 0u;
    __syncthreads();
    for (int i = gtid; i < kN; i += gstride) {          // 8192 elems/block < 65536
        const unsigned bits = __float_as_uint(pred[i]);
        const unsigned b = bits >> 16;
        atomicAdd(&h[b >> 1], (b & 1u) ? 0x10000u : 1u);
    }
    __syncthreads();
    for (int j = t; j < H1_BINS / 2; j += 256) {
        const unsigned v = h[j];
        if (v & 0xFFFFu) atomicAdd(&hist1[2*j],   v & 0xFFFFu);
        if (v >> 16)     atomicAdd(&hist1[2*j+1], v >> 16);
    }
    grid.sync();

    // ---- P5: select1 (block 0): bucket containing order statistic ----
    if (bid == 0) {
        constexpr int PER = H1_BINS / 256;   // 128
        unsigned s = 0;
        for (int j = 0; j < PER; ++j) s += hist1[t*PER + j];
        su[t] = s;
        __syncthreads();
        if (t == 0) { unsigned acc=0; for (int j=0;j<256;++j){ sv[j]=acc; acc+=su[j]; } }
        __syncthreads();
        const unsigned uidx = sel[3];
        if (uidx >= sv[t] && uidx < sv[t] + su[t]) {
            unsigned rank = uidx - sv[t];
            for (int j = 0; j < PER; ++j) {
                const unsigned c = hist1[t*PER + j];
                if (rank < c) { sel[0] = (unsigned)(t*PER + j); sel[1] = rank; break; }
                rank -= c;
            }
        }
    }
    grid.sync();

    // ---- P6: hist2 of low-16 bits within selected bucket ----
    {
        const unsigned bucket = sel[0];
        for (int i = gtid; i < kN; i += gstride) {
            const unsigned bits = __float_as_uint(pred[i]);
            if ((bits >> 16) == bucket) atomicAdd(&hist2[bits & 0xFFFFu], 1u);
        }
    }
    grid.sync();

    // ---- P7: select2 (block 0): exact min_value -> thr ----
    if (bid == 0) {
        constexpr int PER = H2_BINS / 256;   // 256
        unsigned s = 0;
        for (int j = 0; j < PER; ++j) s += hist2[t*PER + j];
        su[t] = s;
        __syncthreads();
        if (t == 0) { unsigned acc=0; for (int j=0;j<256;++j){ sv[j]=acc; acc+=su[j]; } }
        __syncthreads();
        const unsigned rank0 = sel[1];
        if (rank0 >= sv[t] && rank0 < sv[t] + su[t]) {
            unsigned rank = rank0 - sv[t];
            for (int j = 0; j < PER; ++j) {
                const unsigned c = hist2[t*PER + j];
                if (rank < c) {
                    const unsigned bits = (sel[0] << 16) | (unsigned)(t*PER + j);
                    *thr = fmaxf(__uint_as_float(bits), kThresh);
                    break;
                }
                rank -= c;
            }
        }
    }
    grid.sync();

    // ---- P8: reduce with final thr ----
    {
        const float thrv = *thr;
        float num = 0.f; unsigned den = 0;
        for (int i4 = gtid; i4 < kN / 4; i4 += gstride) {
            const float4 p4 = *(const float4*)(pred + i4 * 4);
            const float p[4] = {p4.x, p4.y, p4.z, p4.w};
            #pragma unroll
            for (int q = 0; q < 4; ++q)
                if (p[q] < thrv) { num += -__logf(p[q]); den += 1u; }
        }
        su[t] = den; sf[t] = num;
        __syncthreads();
        for (int o = 128; o > 0; o >>= 1) {
            if (t < o) { su[t]+=su[t+o]; sf[t]+=sf[t+o]; }
            __syncthreads();
        }
        if (t == 0) { pden[bid] = su[0]; pnum[bid] = sf[0]; }
    }
    grid.sync();

    // ---- P9: final (block 0) ----
    if (bid == 0) {
        su[t] = pden[t]; sf[t] = pnum[t];
        __syncthreads();
        for (int o = 128; o > 0; o >>= 1) {
            if (t < o) { su[t]+=su[t+o]; sf[t]+=sf[t+o]; }
            __syncthreads();
        }
        if (t == 0) *ohem_half = 0.5f * (sf[0] / (float)su[0]);
    }
}

// ---------------------------------------------------------------------------
// K3: CE from score0 + broadcast OHEM add, fused. GOLDEN two-phase body
// (hoisted loads); uniform s_load of ohem_half at entry. UNCHANGED from R11.
// ---------------------------------------------------------------------------
__global__ __launch_bounds__(256) void k_ce_out(const float* __restrict__ s0,
                                                const int* __restrict__ tgt,
                                                const float* __restrict__ ohem_half,
                                                float* __restrict__ out)
{
    const float oh = *ohem_half;   // uniform scalar
    const int i4 = blockIdx.x * blockDim.x + threadIdx.x;
    const int i  = i4 * 4;
    const int b  = i >> kHWShift;
    const int hw = i & (kHW - 1);
    const float* p0 = s0 + (size_t)b * kC * kHW + hw;

    float4 v[kC];
    #pragma unroll
    for (int c = 0; c < kC; ++c)
        v[c] = *(const float4*)(p0 + (size_t)c * kHW);   // all independent

    const int4 t4 = *(const int4*)(tgt + i);
    int tt[4] = {t4.x, t4.y, t4.z, t4.w};
    bool mk[4];
    #pragma unroll
    for (int q = 0; q < 4; ++q) {
        mk[q] = (tt[q] != kIgnore);
        tt[q] = mk[q] ? tt[q] : 0;
    }

    float sum[4] = {0.f, 0.f, 0.f, 0.f}, st[4] = {0.f, 0.f, 0.f, 0.f};
    #pragma unroll
    for (int c = 0; c < kC; ++c) {
        const float av[4] = {v[c].x, v[c].y, v[c].z, v[c].w};
        #pragma unroll
        for (int q = 0; q < 4; ++q) {
            sum[q] += __expf(av[q]);
            st[q] = (c == tt[q]) ? av[q] : st[q];
        }
    }

    float4 o4;
    o4.x = (mk[0] ? 0.5f * (__logf(sum[0]) - st[0]) : 0.0f) + oh;
    o4.y = (mk[1] ? 0.5f * (__logf(sum[1]) - st[1]) : 0.0f) + oh;
    o4.z = (mk[2] ? 0.5f * (__logf(sum[2]) - st[2]) : 0.0f) + oh;
    o4.w = (mk[3] ? 0.5f * (__logf(sum[3]) - st[3]) : 0.0f) + oh;
    *(float4*)(out + i) = o4;
}

extern "C" void kernel_launch(void* const* d_in, const int* in_sizes, int n_in,
                              void* d_out, int out_size, void* d_ws, size_t ws_size,
                              hipStream_t stream)
{
    const float* s0  = (const float*)d_in[0];
    const float* s1  = (const float*)d_in[1];
    const int*   tgt = (const int*)d_in[2];
    float* out = (float*)d_out;

    // ws layout
    char* ws = (char*)d_ws;
    float* pred = (float*)ws;                              // kN f32 (8 MB)
    char*  A    = ws + (size_t)kN * 4;
    unsigned int* hist1   = (unsigned int*)A;                          // 128 KB
    unsigned int* hist2   = (unsigned int*)(A + (size_t)H1_BINS * 4);  // 256 KB
    unsigned int* sel     = (unsigned int*)(A + (size_t)(H1_BINS + H2_BINS) * 4); // [bucket,rank,skip,uidx]
    float* thr       = (float*)(sel + 4);
    float* ohem_half = (float*)(sel + 5);
    float*        pnum = (float*)(A + (size_t)(H1_BINS + H2_BINS) * 4 + 256);
    unsigned int* pden = (unsigned int*)(pnum + kOhemBlocks);
    unsigned int* pcnt = pden + kOhemBlocks;
    unsigned int* pcle = pcnt + kOhemBlocks;

    // No memset: all scratch is plain-stored before read; hists are zeroed
    // in-kernel (P3) only when the hist path is taken.

    k_pred<<<kN / 4 / 256, 256, 0, stream>>>(s1, tgt, pred);

    const float* pred_c = pred;
    void* args[] = {(void*)&pred_c, (void*)&pcnt, (void*)&pcle, (void*)&pden,
                    (void*)&pnum, (void*)&sel, (void*)&thr, (void*)&ohem_half,
                    (void*)&hist1, (void*)&hist2};
    hipLaunchCooperativeKernel((const void*)k_ohem, dim3(kOhemBlocks), dim3(256),
                               args, 0, stream);

    k_ce_out<<<kN / 4 / 256, 256, 0, stream>>>(s0, tgt, ohem_half, out);
}

// Round 13
// 87.511 us; speedup vs baseline: 1.5009x; 1.5009x over previous
//
#include <hip/hip_runtime.h>
#include <hip/hip_bf16.h>
#include <stdint.h>

// Problem constants (fixed shapes from setup_inputs)
constexpr int   kC       = 19;
constexpr int   kHW      = 512 * 512;      // 262144 = 2^18
constexpr int   kHWShift = 18;
constexpr int   kN       = 8 * kHW;        // 2097152 pixels
constexpr int   kIgnore  = 255;
constexpr float kThresh  = 0.7f;
constexpr int   kMinKept = 100000;

constexpr int H1_BINS = 32768;   // top-16 bits of a non-negative float
constexpr int H2_BINS = 65536;   // low-16 bits
constexpr int kReduceBlocks = 1024;
constexpr int kCountBlocks  = 256;   // == k_decide block size (1 partial/thread)

// ---------------------------------------------------------------------------
// K1: pred from score1. GOLDEN structure (pure load->compute->one float4
// store; holds the 19-float4 load hoist, ~4.7 TB/s). UNCHANGED since R9.
// ---------------------------------------------------------------------------
__global__ __launch_bounds__(256) void k_pred(const float* __restrict__ s1,
                                              const int* __restrict__ tgt,
                                              float* __restrict__ pred)
{
    const int i4 = blockIdx.x * blockDim.x + threadIdx.x;
    const int i  = i4 * 4;
    const int b  = i >> kHWShift;
    const int hw = i & (kHW - 1);
    const float* p1 = s1 + (size_t)b * kC * kHW + hw;

    float4 v[kC];
    #pragma unroll
    for (int c = 0; c < kC; ++c)
        v[c] = *(const float4*)(p1 + (size_t)c * kHW);   // all independent

    const int4 t4 = *(const int4*)(tgt + i);
    int tt[4] = {t4.x, t4.y, t4.z, t4.w};
    bool mk[4];
    #pragma unroll
    for (int q = 0; q < 4; ++q) {
        mk[q] = (tt[q] != kIgnore);
        tt[q] = mk[q] ? tt[q] : 0;
    }

    float sum[4] = {0.f, 0.f, 0.f, 0.f}, st[4] = {0.f, 0.f, 0.f, 0.f};
    #pragma unroll
    for (int c = 0; c < kC; ++c) {
        const float av[4] = {v[c].x, v[c].y, v[c].z, v[c].w};
        #pragma unroll
        for (int q = 0; q < 4; ++q) {
            sum[q] += __expf(av[q]);
            st[q] = (c == tt[q]) ? av[q] : st[q];
        }
    }

    float4 p4;
    p4.x = mk[0] ? (__expf(st[0]) / sum[0]) : __uint_as_float(0x7f800000u);
    p4.y = mk[1] ? (__expf(st[1]) / sum[1]) : __uint_as_float(0x7f800000u);
    p4.z = mk[2] ? (__expf(st[2]) / sum[2]) : __uint_as_float(0x7f800000u);
    p4.w = mk[3] ? (__expf(st[3]) / sum[3]) : __uint_as_float(0x7f800000u);
    *(float4*)(pred + i) = p4;
}

// ---------------------------------------------------------------------------
// K2: stats pass over pred, zero atomics. Computes per-block partials of:
// cnt (valid), cle (<=0.7), AND the speculative thr=0.7 reduction
// den7 (<0.7), num7 (sum -log p). On the skip path (common case) num7/den7
// IS the final OHEM reduction -> k_reduce/k_final become early-exit stubs.
// ---------------------------------------------------------------------------
__global__ __launch_bounds__(256) void k_count(const float* __restrict__ pred,
                                               unsigned int* __restrict__ pcnt,
                                               unsigned int* __restrict__ pcle,
                                               unsigned int* __restrict__ pden7,
                                               float*        __restrict__ pnum7)
{
    const float inf = __uint_as_float(0x7f800000u);
    int cnt = 0, cle = 0; unsigned den = 0; float num = 0.f;
    const int stride = gridDim.x * blockDim.x;
    for (int i4 = blockIdx.x * blockDim.x + threadIdx.x; i4 < kN / 4; i4 += stride) {
        const float4 p4 = *(const float4*)(pred + i4 * 4);
        const float p[4] = {p4.x, p4.y, p4.z, p4.w};
        #pragma unroll
        for (int q = 0; q < 4; ++q) {
            cnt += (int)(p[q] != inf);
            cle += (int)(p[q] <= kThresh);
            if (p[q] < kThresh) { den += 1u; num += -__logf(p[q]); }  // +inf excluded
        }
    }
    __shared__ unsigned int su[256], sv[256], sw[256];
    __shared__ float sf[256];
    const int t = threadIdx.x;
    su[t] = (unsigned)cnt; sv[t] = (unsigned)cle; sw[t] = den; sf[t] = num;
    __syncthreads();
    for (int o = 128; o > 0; o >>= 1) {
        if (t < o) { su[t]+=su[t+o]; sv[t]+=sv[t+o]; sw[t]+=sw[t+o]; sf[t]+=sf[t+o]; }
        __syncthreads();
    }
    if (t == 0) {
        pcnt[blockIdx.x] = su[0]; pcle[blockIdx.x] = sv[0];
        pden7[blockIdx.x] = sw[0]; pnum7[blockIdx.x] = sf[0];
    }
}

// ---------------------------------------------------------------------------
// K3: decide (1 block). Sum 256 partials; idx = clamp(min(MIN_KEPT,
// n_valid-1), 0); if cnt_le >= idx+1 -> threshold = 0.7 exactly, and the
// speculative num7/den7 is the final answer: write ohem_half, skip the rest.
// ---------------------------------------------------------------------------
__global__ __launch_bounds__(256) void k_decide(const unsigned int* __restrict__ pcnt,
                                                const unsigned int* __restrict__ pcle,
                                                const unsigned int* __restrict__ pden7,
                                                const float*        __restrict__ pnum7,
                                                unsigned int* __restrict__ sel,
                                                float* __restrict__ thr,
                                                float* __restrict__ ohem_half)
{
    __shared__ unsigned int su[256], sv[256], sw[256];
    __shared__ float sf[256];
    const int t = threadIdx.x;
    su[t] = pcnt[t]; sv[t] = pcle[t]; sw[t] = pden7[t]; sf[t] = pnum7[t];
    __syncthreads();
    for (int o = 128; o > 0; o >>= 1) {
        if (t < o) { su[t]+=su[t+o]; sv[t]+=sv[t+o]; sw[t]+=sw[t+o]; sf[t]+=sf[t+o]; }
        __syncthreads();
    }
    if (t == 0) {
        const unsigned int n_valid = su[0];
        const unsigned int cnt_le  = sv[0];
        long long idx = (long long)n_valid - 1;
        if (idx > kMinKept) idx = kMinKept;
        if (idx < 0) idx = 0;
        const unsigned int uidx = (unsigned int)idx;
        sel[3] = uidx;
        const bool skip = (cnt_le >= uidx + 1);   // sorted[idx] <= 0.7
        sel[2] = skip ? 1u : 0u;
        *thr = kThresh;                            // overwritten iff hist path runs
        if (skip) *ohem_half = 0.5f * (sf[0] / (float)sw[0]);
    }
}

// ---------------------------------------------------------------------------
// K4: zero hist buffers — only on the hist path. 384 KB via uint4 stores.
// ---------------------------------------------------------------------------
__global__ __launch_bounds__(256) void k_zero_hists(const unsigned int* __restrict__ sel,
                                                    uint4* __restrict__ hists)
{
    if (sel[2]) return;
    const int j = blockIdx.x * blockDim.x + threadIdx.x;   // 96*256 = 24576 uint4
    hists[j] = make_uint4(0u, 0u, 0u, 0u);
}

// ---------------------------------------------------------------------------
// K5: histogram of top-16 bits of pred bits (skipped when threshold=0.7).
// ---------------------------------------------------------------------------
__global__ __launch_bounds__(256) void k_hist1(const float* __restrict__ pred,
                                               const unsigned int* __restrict__ sel,
                                               unsigned int* __restrict__ hist1)
{
    if (sel[2]) return;
    __shared__ unsigned int h[H1_BINS / 2];   // 64 KB, packed 2x u16
    for (int j = threadIdx.x; j < H1_BINS / 2; j += 256) h[j] = 0u;
    __syncthreads();
    int stride = gridDim.x * blockDim.x;
    for (int i = blockIdx.x * blockDim.x + threadIdx.x; i < kN; i += stride) {
        unsigned int bits = __float_as_uint(pred[i]);
        unsigned int b = bits >> 16;
        atomicAdd(&h[b >> 1], (b & 1u) ? 0x10000u : 1u);
    }
    __syncthreads();
    for (int j = threadIdx.x; j < H1_BINS / 2; j += 256) {
        unsigned int v = h[j];
        if (v & 0xFFFFu) atomicAdd(&hist1[2 * j],     v & 0xFFFFu);
        if (v >> 16)     atomicAdd(&hist1[2 * j + 1], v >> 16);
    }
}

// ---------------------------------------------------------------------------
// K6: find bucket containing order statistic sel[3]
// ---------------------------------------------------------------------------
__global__ __launch_bounds__(256) void k_select1(const unsigned int* __restrict__ hist1,
                                                 unsigned int* __restrict__ sel)
{
    if (sel[2]) return;
    __shared__ unsigned int sums[256];
    __shared__ unsigned int excl[256];
    int t = threadIdx.x;
    constexpr int PER = H1_BINS / 256;   // 128
    unsigned int s = 0;
    for (int j = 0; j < PER; ++j) s += hist1[t * PER + j];
    sums[t] = s;
    __syncthreads();
    if (t == 0) {
        unsigned int acc = 0;
        for (int j = 0; j < 256; ++j) { excl[j] = acc; acc += sums[j]; }
    }
    __syncthreads();
    unsigned int uidx = sel[3];
    if (uidx >= excl[t] && uidx < excl[t] + sums[t]) {
        unsigned int rank = uidx - excl[t];
        for (int j = 0; j < PER; ++j) {
            unsigned int c = hist1[t * PER + j];
            if (rank < c) { sel[0] = (unsigned int)(t * PER + j); sel[1] = rank; break; }
            rank -= c;
        }
    }
}

// ---------------------------------------------------------------------------
// K7: refine — histogram low-16 bits within selected bucket
// ---------------------------------------------------------------------------
__global__ __launch_bounds__(256) void k_hist2(const float* __restrict__ pred,
                                               const unsigned int* __restrict__ sel,
                                               unsigned int* __restrict__ hist2)
{
    if (sel[2]) return;
    unsigned int bucket = sel[0];
    int stride = gridDim.x * blockDim.x;
    for (int i = blockIdx.x * blockDim.x + threadIdx.x; i < kN; i += stride) {
        unsigned int bits = __float_as_uint(pred[i]);
        if ((bits >> 16) == bucket) atomicAdd(&hist2[bits & 0xFFFFu], 1u);
    }
}

// ---------------------------------------------------------------------------
// K8: exact min_value; threshold = max(min_value, 0.7)
// ---------------------------------------------------------------------------
__global__ __launch_bounds__(256) void k_select2(const unsigned int* __restrict__ hist2,
                                                 const unsigned int* __restrict__ sel,
                                                 float* __restrict__ thr)
{
    if (sel[2]) return;
    __shared__ unsigned int sums[256];
    __shared__ unsigned int excl[256];
    int t = threadIdx.x;
    constexpr int PER = H2_BINS / 256;   // 256
    unsigned int s = 0;
    for (int j = 0; j < PER; ++j) s += hist2[t * PER + j];
    sums[t] = s;
    __syncthreads();
    if (t == 0) {
        unsigned int acc = 0;
        for (int j = 0; j < 256; ++j) { excl[j] = acc; acc += sums[j]; }
    }
    __syncthreads();
    unsigned int rank0 = sel[1];
    if (rank0 >= excl[t] && rank0 < excl[t] + sums[t]) {
        unsigned int rank = rank0 - excl[t];
        for (int j = 0; j < PER; ++j) {
            unsigned int c = hist2[t * PER + j];
            if (rank < c) {
                unsigned int bits = (sel[0] << 16) | (unsigned int)(t * PER + j);
                *thr = fmaxf(__uint_as_float(bits), kThresh);
                break;
            }
            rank -= c;
        }
    }
}

// ---------------------------------------------------------------------------
// K9: hist-path-only reduce with the exact threshold (early-exits on skip —
// the skip-path answer was already produced by k_count/k_decide).
// ---------------------------------------------------------------------------
__global__ __launch_bounds__(256) void k_reduce(const float* __restrict__ pred,
                                                const unsigned int* __restrict__ sel,
                                                const float* __restrict__ thr_p,
                                                float* __restrict__ pnum,
                                                unsigned int* __restrict__ pden)
{
    if (sel[2]) return;
    const float thr = *thr_p;
    float num = 0.f; unsigned int den = 0;
    const int stride = gridDim.x * blockDim.x;
    for (int i4 = blockIdx.x * blockDim.x + threadIdx.x; i4 < kN / 4; i4 += stride) {
        const float4 p4 = *(const float4*)(pred + i4 * 4);
        const float p[4] = {p4.x, p4.y, p4.z, p4.w};
        #pragma unroll
        for (int v = 0; v < 4; ++v) {
            if (p[v] < thr) { num += -__logf(p[v]); den += 1u; }  // +inf never kept
        }
    }
    __shared__ float sn[256]; __shared__ unsigned int sd[256];
    int t = threadIdx.x;
    sn[t] = num; sd[t] = den; __syncthreads();
    for (int o = 128; o > 0; o >>= 1) {
        if (t < o) { sn[t] += sn[t + o]; sd[t] += sd[t + o]; }
        __syncthreads();
    }
    if (t == 0) { pnum[blockIdx.x] = sn[0]; pden[blockIdx.x] = sd[0]; }
}

// ---------------------------------------------------------------------------
// K10: hist-path-only final scalar (early-exits on skip)
// ---------------------------------------------------------------------------
__global__ __launch_bounds__(256) void k_final_scalar(const unsigned int* __restrict__ sel,
                                                      const float* __restrict__ pnum,
                                                      const unsigned int* __restrict__ pden,
                                                      float* __restrict__ ohem_half)
{
    if (sel[2]) return;
    int t = threadIdx.x;
    float num = 0.f; unsigned int den = 0;
    for (int j = t; j < kReduceBlocks; j += 256) { num += pnum[j]; den += pden[j]; }
    __shared__ float sn[256]; __shared__ unsigned int sd[256];
    sn[t] = num; sd[t] = den; __syncthreads();
    for (int o = 128; o > 0; o >>= 1) {
        if (t < o) { sn[t] += sn[t + o]; sd[t] += sd[t + o]; }
        __syncthreads();
    }
    if (t == 0) *ohem_half = 0.5f * (sn[0] / (float)sd[0]);
}

// ---------------------------------------------------------------------------
// K11: CE from score0 + broadcast OHEM add, fused. GOLDEN two-phase body
// (hoisted loads); uniform s_load of ohem_half at entry. UNCHANGED from R11.
// ---------------------------------------------------------------------------
__global__ __launch_bounds__(256) void k_ce_out(const float* __restrict__ s0,
                                                const int* __restrict__ tgt,
                                                const float* __restrict__ ohem_half,
                                                float* __restrict__ out)
{
    const float oh = *ohem_half;   // uniform scalar
    const int i4 = blockIdx.x * blockDim.x + threadIdx.x;
    const int i  = i4 * 4;
    const int b  = i >> kHWShift;
    const int hw = i & (kHW - 1);
    const float* p0 = s0 + (size_t)b * kC * kHW + hw;

    float4 v[kC];
    #pragma unroll
    for (int c = 0; c < kC; ++c)
        v[c] = *(const float4*)(p0 + (size_t)c * kHW);   // all independent

    const int4 t4 = *(const int4*)(tgt + i);
    int tt[4] = {t4.x, t4.y, t4.z, t4.w};
    bool mk[4];
    #pragma unroll
    for (int q = 0; q < 4; ++q) {
        mk[q] = (tt[q] != kIgnore);
        tt[q] = mk[q] ? tt[q] : 0;
    }

    float sum[4] = {0.f, 0.f, 0.f, 0.f}, st[4] = {0.f, 0.f, 0.f, 0.f};
    #pragma unroll
    for (int c = 0; c < kC; ++c) {
        const float av[4] = {v[c].x, v[c].y, v[c].z, v[c].w};
        #pragma unroll
        for (int q = 0; q < 4; ++q) {
            sum[q] += __expf(av[q]);
            st[q] = (c == tt[q]) ? av[q] : st[q];
        }
    }

    float4 o4;
    o4.x = (mk[0] ? 0.5f * (__logf(sum[0]) - st[0]) : 0.0f) + oh;
    o4.y = (mk[1] ? 0.5f * (__logf(sum[1]) - st[1]) : 0.0f) + oh;
    o4.z = (mk[2] ? 0.5f * (__logf(sum[2]) - st[2]) : 0.0f) + oh;
    o4.w = (mk[3] ? 0.5f * (__logf(sum[3]) - st[3]) : 0.0f) + oh;
    *(float4*)(out + i) = o4;
}

extern "C" void kernel_launch(void* const* d_in, const int* in_sizes, int n_in,
                              void* d_out, int out_size, void* d_ws, size_t ws_size,
                              hipStream_t stream)
{
    const float* s0  = (const float*)d_in[0];
    const float* s1  = (const float*)d_in[1];
    const int*   tgt = (const int*)d_in[2];
    float* out = (float*)d_out;

    // ws layout
    char* ws = (char*)d_ws;
    float* pred = (float*)ws;                              // kN f32 (8 MB)
    char*  A    = ws + (size_t)kN * 4;
    unsigned int* hist1   = (unsigned int*)A;                          // 128 KB
    unsigned int* hist2   = (unsigned int*)(A + (size_t)H1_BINS * 4);  // 256 KB
    unsigned int* sel     = (unsigned int*)(A + (size_t)(H1_BINS + H2_BINS) * 4); // [bucket,rank,skip,uidx]
    float* thr       = (float*)(sel + 4);
    float* ohem_half = (float*)(sel + 5);
    float*        pnum  = (float*)(A + (size_t)(H1_BINS + H2_BINS) * 4 + 256);
    unsigned int* pden  = (unsigned int*)(pnum + kReduceBlocks);
    unsigned int* pcnt  = pden + kReduceBlocks;            // 256 partials
    unsigned int* pcle  = pcnt + kCountBlocks;             // 256 partials
    unsigned int* pden7 = pcle + kCountBlocks;             // 256 partials
    float*        pnum7 = (float*)(pden7 + kCountBlocks);  // 256 partials

    // No memset: all scratch is plain-stored before read; hist buffers are
    // zeroed by k_zero_hists only when the hist path is taken.

    k_pred <<<kN / 4 / 256, 256, 0, stream>>>(s1, tgt, pred);
    k_count<<<kCountBlocks, 256, 0, stream>>>(pred, pcnt, pcle, pden7, pnum7);
    k_decide<<<1, 256, 0, stream>>>(pcnt, pcle, pden7, pnum7, sel, thr, ohem_half);
    k_zero_hists<<<(H1_BINS + H2_BINS) / 4 / 256, 256, 0, stream>>>(sel, (uint4*)A);
    k_hist1<<<256, 256, 0, stream>>>(pred, sel, hist1);
    k_select1<<<1, 256, 0, stream>>>(hist1, sel);
    k_hist2<<<2048, 256, 0, stream>>>(pred, sel, hist2);
    k_select2<<<1, 256, 0, stream>>>(hist2, sel, thr);
    k_reduce<<<kReduceBlocks, 256, 0, stream>>>(pred, sel, thr, pnum, pden);
    k_final_scalar<<<1, 256, 0, stream>>>(sel, pnum, pden, ohem_half);
    k_ce_out<<<kN / 4 / 256, 256, 0, stream>>>(s0, tgt, ohem_half, out);
}

// Round 15
// 72.321 us; speedup vs baseline: 1.8161x; 1.2100x over previous
//
#include <hip/hip_runtime.h>
#include <hip/hip_bf16.h>
#include <stdint.h>

// Problem constants (fixed shapes from setup_inputs)
constexpr int   kC       = 19;
constexpr int   kHW      = 512 * 512;      // 262144 = 2^18
constexpr int   kHWShift = 18;
constexpr int   kN       = 8 * kHW;        // 2097152 pixels
constexpr int   kIgnore  = 255;
constexpr float kThresh  = 0.7f;
constexpr int   kMinKept = 100000;

constexpr int H1_BINS = 32768;   // top-16 bits of a non-negative float
constexpr int H2_BINS = 65536;   // low-16 bits
constexpr int kCountBlocks = 256;   // == k_decide block size (1 partial/thread)

// native vector type for __builtin_nontemporal_load (HIP float4 is a class)
typedef float f32x4 __attribute__((ext_vector_type(4)));

// ---------------------------------------------------------------------------
// K1a: pred from score1, FIRST HALF of pixels. GOLDEN structure (pure
// load->compute->one float4 store; holds the 19-float4 load hoist).
// Byte-identical body to R9-R13's k_pred, range-restricted.
// ---------------------------------------------------------------------------
__global__ __launch_bounds__(256) void k_pred_a(const float* __restrict__ s1,
                                                const int* __restrict__ tgt,
                                                float* __restrict__ pred)
{
    const int i4 = blockIdx.x * blockDim.x + threadIdx.x;   // [0, kN/8)
    const int i  = i4 * 4;
    const int b  = i >> kHWShift;
    const int hw = i & (kHW - 1);
    const float* p1 = s1 + (size_t)b * kC * kHW + hw;

    float4 v[kC];
    #pragma unroll
    for (int c = 0; c < kC; ++c)
        v[c] = *(const float4*)(p1 + (size_t)c * kHW);   // all independent

    const int4 t4 = *(const int4*)(tgt + i);
    int tt[4] = {t4.x, t4.y, t4.z, t4.w};
    bool mk[4];
    #pragma unroll
    for (int q = 0; q < 4; ++q) {
        mk[q] = (tt[q] != kIgnore);
        tt[q] = mk[q] ? tt[q] : 0;
    }

    float sum[4] = {0.f, 0.f, 0.f, 0.f}, st[4] = {0.f, 0.f, 0.f, 0.f};
    #pragma unroll
    for (int c = 0; c < kC; ++c) {
        const float av[4] = {v[c].x, v[c].y, v[c].z, v[c].w};
        #pragma unroll
        for (int q = 0; q < 4; ++q) {
            sum[q] += __expf(av[q]);
            st[q] = (c == tt[q]) ? av[q] : st[q];
        }
    }

    float4 p4;
    p4.x = mk[0] ? (__expf(st[0]) / sum[0]) : __uint_as_float(0x7f800000u);
    p4.y = mk[1] ? (__expf(st[1]) / sum[1]) : __uint_as_float(0x7f800000u);
    p4.z = mk[2] ? (__expf(st[2]) / sum[2]) : __uint_as_float(0x7f800000u);
    p4.w = mk[3] ? (__expf(st[3]) / sum[3]) : __uint_as_float(0x7f800000u);
    *(float4*)(pred + i) = p4;
}

// ---------------------------------------------------------------------------
// K1b: pred, SECOND HALF — A/B variant: nontemporal loads (via ext_vector
// f32x4 — HIP float4 class rejected by the builtin) on the 19 read-once
// score streams (318 MB >> L3; nt avoids evicting pred/tgt from L2/L3).
// Same-run dur_us comparison vs k_pred_a decides promotion next round.
// ---------------------------------------------------------------------------
__global__ __launch_bounds__(256) void k_pred_b(const float* __restrict__ s1,
                                                const int* __restrict__ tgt,
                                                float* __restrict__ pred)
{
    const int i4 = (kN / 8) + blockIdx.x * blockDim.x + threadIdx.x;  // [kN/8, kN/4)
    const int i  = i4 * 4;
    const int b  = i >> kHWShift;
    const int hw = i & (kHW - 1);
    const float* p1 = s1 + (size_t)b * kC * kHW + hw;

    f32x4 v[kC];
    #pragma unroll
    for (int c = 0; c < kC; ++c)
        v[c] = __builtin_nontemporal_load((const f32x4*)(p1 + (size_t)c * kHW));

    const int4 t4 = *(const int4*)(tgt + i);
    int tt[4] = {t4.x, t4.y, t4.z, t4.w};
    bool mk[4];
    #pragma unroll
    for (int q = 0; q < 4; ++q) {
        mk[q] = (tt[q] != kIgnore);
        tt[q] = mk[q] ? tt[q] : 0;
    }

    float sum[4] = {0.f, 0.f, 0.f, 0.f}, st[4] = {0.f, 0.f, 0.f, 0.f};
    #pragma unroll
    for (int c = 0; c < kC; ++c) {
        const float av[4] = {v[c][0], v[c][1], v[c][2], v[c][3]};
        #pragma unroll
        for (int q = 0; q < 4; ++q) {
            sum[q] += __expf(av[q]);
            st[q] = (c == tt[q]) ? av[q] : st[q];
        }
    }

    float4 p4;
    p4.x = mk[0] ? (__expf(st[0]) / sum[0]) : __uint_as_float(0x7f800000u);
    p4.y = mk[1] ? (__expf(st[1]) / sum[1]) : __uint_as_float(0x7f800000u);
    p4.z = mk[2] ? (__expf(st[2]) / sum[2]) : __uint_as_float(0x7f800000u);
    p4.w = mk[3] ? (__expf(st[3]) / sum[3]) : __uint_as_float(0x7f800000u);
    *(float4*)(pred + i) = p4;
}

// ---------------------------------------------------------------------------
// K2: stats pass over pred, zero atomics: cnt (valid), cle (<=0.7), and the
// speculative thr=0.7 reduction den7/num7 (final answer on the skip path).
// UNCHANGED from R13.
// ---------------------------------------------------------------------------
__global__ __launch_bounds__(256) void k_count(const float* __restrict__ pred,
                                               unsigned int* __restrict__ pcnt,
                                               unsigned int* __restrict__ pcle,
                                               unsigned int* __restrict__ pden7,
                                               float*        __restrict__ pnum7)
{
    const float inf = __uint_as_float(0x7f800000u);
    int cnt = 0, cle = 0; unsigned den = 0; float num = 0.f;
    const int stride = gridDim.x * blockDim.x;
    for (int i4 = blockIdx.x * blockDim.x + threadIdx.x; i4 < kN / 4; i4 += stride) {
        const float4 p4 = *(const float4*)(pred + i4 * 4);
        const float p[4] = {p4.x, p4.y, p4.z, p4.w};
        #pragma unroll
        for (int q = 0; q < 4; ++q) {
            cnt += (int)(p[q] != inf);
            cle += (int)(p[q] <= kThresh);
            if (p[q] < kThresh) { den += 1u; num += -__logf(p[q]); }  // +inf excluded
        }
    }
    __shared__ unsigned int su[256], sv[256], sw[256];
    __shared__ float sf[256];
    const int t = threadIdx.x;
    su[t] = (unsigned)cnt; sv[t] = (unsigned)cle; sw[t] = den; sf[t] = num;
    __syncthreads();
    for (int o = 128; o > 0; o >>= 1) {
        if (t < o) { su[t]+=su[t+o]; sv[t]+=sv[t+o]; sw[t]+=sw[t+o]; sf[t]+=sf[t+o]; }
        __syncthreads();
    }
    if (t == 0) {
        pcnt[blockIdx.x] = su[0]; pcle[blockIdx.x] = sv[0];
        pden7[blockIdx.x] = sw[0]; pnum7[blockIdx.x] = sf[0];
    }
}

// ---------------------------------------------------------------------------
// K3: decide + COMPLETE fallback hist path, one block (replaces 8 launches).
// Skip path (sorted[idx] <= 0.7, always taken on this data): sum partials,
// write ohem_half, exit — ~1 µs. Hist path (general inputs): the full
// two-level radix select + exact reduce runs serially in this block using
// the global hist buffers (slow — hundreds of µs — but exact, deterministic,
// and never exercised by data where the 100000th-smallest prob <= 0.7).
// ---------------------------------------------------------------------------
__global__ __launch_bounds__(256) void k_decide(const unsigned int* __restrict__ pcnt,
                                                const unsigned int* __restrict__ pcle,
                                                const unsigned int* __restrict__ pden7,
                                                const float*        __restrict__ pnum7,
                                                const float* __restrict__ pred,
                                                unsigned int* __restrict__ hist1,
                                                unsigned int* __restrict__ hist2,
                                                float* __restrict__ ohem_half)
{
    __shared__ unsigned int su[256], sv[256], sw[256];
    __shared__ float sf[256];
    __shared__ unsigned int meta[4];   // [skip, uidx, bucket, rank]
    __shared__ float sthr;
    const int t = threadIdx.x;

    su[t] = pcnt[t]; sv[t] = pcle[t]; sw[t] = pden7[t]; sf[t] = pnum7[t];
    __syncthreads();
    for (int o = 128; o > 0; o >>= 1) {
        if (t < o) { su[t]+=su[t+o]; sv[t]+=sv[t+o]; sw[t]+=sw[t+o]; sf[t]+=sf[t+o]; }
        __syncthreads();
    }
    if (t == 0) {
        const unsigned n_valid = su[0], cnt_le = sv[0];
        long long idx = (long long)n_valid - 1;
        if (idx > kMinKept) idx = kMinKept;
        if (idx < 0) idx = 0;
        const unsigned uidx = (unsigned)idx;
        const bool skip = (cnt_le >= uidx + 1);   // sorted[idx] <= 0.7 -> thr = 0.7
        meta[0] = skip ? 1u : 0u;
        meta[1] = uidx;
        if (skip) *ohem_half = 0.5f * (sf[0] / (float)sw[0]);
    }
    __syncthreads();
    if (meta[0]) return;                          // common case: done

    // ---------- fallback: exact threshold via two-level radix select ----------
    for (int j = t; j < H1_BINS + H2_BINS; j += 256)
        (j < H1_BINS ? hist1[j] : hist2[j - H1_BINS]) = 0u;
    __syncthreads();
    // pass 1: top-16-bit histogram
    for (int i = t; i < kN; i += 256) {
        const unsigned bits = __float_as_uint(pred[i]);
        atomicAdd(&hist1[bits >> 16], 1u);
    }
    __syncthreads();
    // select bucket
    {
        constexpr int PER = H1_BINS / 256;   // 128
        unsigned s = 0;
        for (int j = 0; j < PER; ++j) s += hist1[t * PER + j];
        su[t] = s;
        __syncthreads();
        if (t == 0) { unsigned acc = 0; for (int j = 0; j < 256; ++j) { sv[j] = acc; acc += su[j]; } }
        __syncthreads();
        const unsigned uidx = meta[1];
        if (uidx >= sv[t] && uidx < sv[t] + su[t]) {
            unsigned rank = uidx - sv[t];
            for (int j = 0; j < PER; ++j) {
                const unsigned c = hist1[t * PER + j];
                if (rank < c) { meta[2] = (unsigned)(t * PER + j); meta[3] = rank; break; }
                rank -= c;
            }
        }
    }
    __syncthreads();
    // pass 2: low-16-bit histogram within bucket
    {
        const unsigned bucket = meta[2];
        for (int i = t; i < kN; i += 256) {
            const unsigned bits = __float_as_uint(pred[i]);
            if ((bits >> 16) == bucket) atomicAdd(&hist2[bits & 0xFFFFu], 1u);
        }
    }
    __syncthreads();
    // select exact min_value -> thr
    {
        constexpr int PER = H2_BINS / 256;   // 256
        unsigned s = 0;
        for (int j = 0; j < PER; ++j) s += hist2[t * PER + j];
        su[t] = s;
        __syncthreads();
        if (t == 0) { unsigned acc = 0; for (int j = 0; j < 256; ++j) { sv[j] = acc; acc += su[j]; } }
        __syncthreads();
        const unsigned rank0 = meta[3];
        if (rank0 >= sv[t] && rank0 < sv[t] + su[t]) {
            unsigned rank = rank0 - sv[t];
            for (int j = 0; j < PER; ++j) {
                const unsigned c = hist2[t * PER + j];
                if (rank < c) {
                    const unsigned bits = (meta[2] << 16) | (unsigned)(t * PER + j);
                    sthr = fmaxf(__uint_as_float(bits), kThresh);
                    break;
                }
                rank -= c;
            }
        }
    }
    __syncthreads();
    // exact reduce with final thr
    {
        const float thrv = sthr;
        float num = 0.f; unsigned den = 0;
        for (int i4 = t; i4 < kN / 4; i4 += 256) {
            const float4 p4 = *(const float4*)(pred + i4 * 4);
            const float p[4] = {p4.x, p4.y, p4.z, p4.w};
            #pragma unroll
            for (int q = 0; q < 4; ++q)
                if (p[q] < thrv) { num += -__logf(p[q]); den += 1u; }
        }
        su[t] = den; sf[t] = num;
        __syncthreads();
        for (int o = 128; o > 0; o >>= 1) {
            if (t < o) { su[t]+=su[t+o]; sf[t]+=sf[t+o]; }
            __syncthreads();
        }
        if (t == 0) *ohem_half = 0.5f * (sf[0] / (float)su[0]);
    }
}

// ---------------------------------------------------------------------------
// K4: CE from score0 + broadcast OHEM add, fused. GOLDEN two-phase body
// (hoisted loads); uniform s_load of ohem_half at entry. UNCHANGED from R11.
// ---------------------------------------------------------------------------
__global__ __launch_bounds__(256) void k_ce_out(const float* __restrict__ s0,
                                                const int* __restrict__ tgt,
                                                const float* __restrict__ ohem_half,
                                                float* __restrict__ out)
{
    const float oh = *ohem_half;   // uniform scalar
    const int i4 = blockIdx.x * blockDim.x + threadIdx.x;
    const int i  = i4 * 4;
    const int b  = i >> kHWShift;
    const int hw = i & (kHW - 1);
    const float* p0 = s0 + (size_t)b * kC * kHW + hw;

    float4 v[kC];
    #pragma unroll
    for (int c = 0; c < kC; ++c)
        v[c] = *(const float4*)(p0 + (size_t)c * kHW);   // all independent

    const int4 t4 = *(const int4*)(tgt + i);
    int tt[4] = {t4.x, t4.y, t4.z, t4.w};
    bool mk[4];
    #pragma unroll
    for (int q = 0; q < 4; ++q) {
        mk[q] = (tt[q] != kIgnore);
        tt[q] = mk[q] ? tt[q] : 0;
    }

    float sum[4] = {0.f, 0.f, 0.f, 0.f}, st[4] = {0.f, 0.f, 0.f, 0.f};
    #pragma unroll
    for (int c = 0; c < kC; ++c) {
        const float av[4] = {v[c].x, v[c].y, v[c].z, v[c].w};
        #pragma unroll
        for (int q = 0; q < 4; ++q) {
            sum[q] += __expf(av[q]);
            st[q] = (c == tt[q]) ? av[q] : st[q];
        }
    }

    float4 o4;
    o4.x = (mk[0] ? 0.5f * (__logf(sum[0]) - st[0]) : 0.0f) + oh;
    o4.y = (mk[1] ? 0.5f * (__logf(sum[1]) - st[1]) : 0.0f) + oh;
    o4.z = (mk[2] ? 0.5f * (__logf(sum[2]) - st[2]) : 0.0f) + oh;
    o4.w = (mk[3] ? 0.5f * (__logf(sum[3]) - st[3]) : 0.0f) + oh;
    *(float4*)(out + i) = o4;
}

extern "C" void kernel_launch(void* const* d_in, const int* in_sizes, int n_in,
                              void* d_out, int out_size, void* d_ws, size_t ws_size,
                              hipStream_t stream)
{
    const float* s0  = (const float*)d_in[0];
    const float* s1  = (const float*)d_in[1];
    const int*   tgt = (const int*)d_in[2];
    float* out = (float*)d_out;

    // ws layout
    char* ws = (char*)d_ws;
    float* pred = (float*)ws;                              // kN f32 (8 MB)
    char*  A    = ws + (size_t)kN * 4;
    unsigned int* hist1 = (unsigned int*)A;                            // 128 KB
    unsigned int* hist2 = (unsigned int*)(A + (size_t)H1_BINS * 4);    // 256 KB
    float* ohem_half    = (float*)(A + (size_t)(H1_BINS + H2_BINS) * 4);
    unsigned int* pcnt  = (unsigned int*)(ohem_half + 1);  // 256 partials
    unsigned int* pcle  = pcnt + kCountBlocks;
    unsigned int* pden7 = pcle + kCountBlocks;
    float*        pnum7 = (float*)(pden7 + kCountBlocks);

    // No memset anywhere: all scratch plain-stored before read; hist buffers
    // are zeroed inside k_decide's fallback branch only.

    k_pred_a<<<kN / 8 / 256, 256, 0, stream>>>(s1, tgt, pred);
    k_pred_b<<<kN / 8 / 256, 256, 0, stream>>>(s1, tgt, pred);
    k_count <<<kCountBlocks, 256, 0, stream>>>(pred, pcnt, pcle, pden7, pnum7);
    k_decide<<<1, 256, 0, stream>>>(pcnt, pcle, pden7, pnum7, pred,
                                    hist1, hist2, ohem_half);
    k_ce_out<<<kN / 4 / 256, 256, 0, stream>>>(s0, tgt, ohem_half, out);
}

// Round 16
// 69.710 us; speedup vs baseline: 1.8842x; 1.0375x over previous
//
#include <hip/hip_runtime.h>
#include <hip/hip_bf16.h>
#include <stdint.h>

// Problem constants (fixed shapes from setup_inputs)
constexpr int   kC       = 19;
constexpr int   kHW      = 512 * 512;      // 262144 = 2^18
constexpr int   kHWShift = 18;
constexpr int   kN       = 8 * kHW;        // 2097152 pixels
constexpr int   kIgnore  = 255;
constexpr float kThresh  = 0.7f;
constexpr int   kMinKept = 100000;

constexpr int H1_BINS = 32768;   // top-16 bits of a non-negative float
constexpr int H2_BINS = 65536;   // low-16 bits
constexpr int kCountBlocks = 256;   // == k_decide block size (1 partial/thread)

// native vector type for __builtin_nontemporal_load (HIP float4 is a class)
typedef float f32x4 __attribute__((ext_vector_type(4)));

// ---------------------------------------------------------------------------
// K1: pred from score1, full range, NONTEMPORAL score loads (promoted from
// R15's winning k_pred_b A/B arm). Golden two-phase structure: hoist all 19
// independent loads, then consume; pure load->compute->one float4 store.
// ---------------------------------------------------------------------------
__global__ __launch_bounds__(256) void k_pred(const float* __restrict__ s1,
                                              const int* __restrict__ tgt,
                                              float* __restrict__ pred)
{
    const int i4 = blockIdx.x * blockDim.x + threadIdx.x;
    const int i  = i4 * 4;
    const int b  = i >> kHWShift;
    const int hw = i & (kHW - 1);
    const float* p1 = s1 + (size_t)b * kC * kHW + hw;

    f32x4 v[kC];
    #pragma unroll
    for (int c = 0; c < kC; ++c)
        v[c] = __builtin_nontemporal_load((const f32x4*)(p1 + (size_t)c * kHW));

    const int4 t4 = *(const int4*)(tgt + i);
    int tt[4] = {t4.x, t4.y, t4.z, t4.w};
    bool mk[4];
    #pragma unroll
    for (int q = 0; q < 4; ++q) {
        mk[q] = (tt[q] != kIgnore);
        tt[q] = mk[q] ? tt[q] : 0;
    }

    float sum[4] = {0.f, 0.f, 0.f, 0.f}, st[4] = {0.f, 0.f, 0.f, 0.f};
    #pragma unroll
    for (int c = 0; c < kC; ++c) {
        const float av[4] = {v[c][0], v[c][1], v[c][2], v[c][3]};
        #pragma unroll
        for (int q = 0; q < 4; ++q) {
            sum[q] += __expf(av[q]);
            st[q] = (c == tt[q]) ? av[q] : st[q];
        }
    }

    float4 p4;
    p4.x = mk[0] ? (__expf(st[0]) / sum[0]) : __uint_as_float(0x7f800000u);
    p4.y = mk[1] ? (__expf(st[1]) / sum[1]) : __uint_as_float(0x7f800000u);
    p4.z = mk[2] ? (__expf(st[2]) / sum[2]) : __uint_as_float(0x7f800000u);
    p4.w = mk[3] ? (__expf(st[3]) / sum[3]) : __uint_as_float(0x7f800000u);
    *(float4*)(pred + i) = p4;
}

// ---------------------------------------------------------------------------
// K2: stats pass over pred, zero atomics: cnt (valid), cle (<=0.7), and the
// speculative thr=0.7 reduction den7/num7 (final answer on the skip path).
// UNCHANGED from R13.
// ---------------------------------------------------------------------------
__global__ __launch_bounds__(256) void k_count(const float* __restrict__ pred,
                                               unsigned int* __restrict__ pcnt,
                                               unsigned int* __restrict__ pcle,
                                               unsigned int* __restrict__ pden7,
                                               float*        __restrict__ pnum7)
{
    const float inf = __uint_as_float(0x7f800000u);
    int cnt = 0, cle = 0; unsigned den = 0; float num = 0.f;
    const int stride = gridDim.x * blockDim.x;
    for (int i4 = blockIdx.x * blockDim.x + threadIdx.x; i4 < kN / 4; i4 += stride) {
        const float4 p4 = *(const float4*)(pred + i4 * 4);
        const float p[4] = {p4.x, p4.y, p4.z, p4.w};
        #pragma unroll
        for (int q = 0; q < 4; ++q) {
            cnt += (int)(p[q] != inf);
            cle += (int)(p[q] <= kThresh);
            if (p[q] < kThresh) { den += 1u; num += -__logf(p[q]); }  // +inf excluded
        }
    }
    __shared__ unsigned int su[256], sv[256], sw[256];
    __shared__ float sf[256];
    const int t = threadIdx.x;
    su[t] = (unsigned)cnt; sv[t] = (unsigned)cle; sw[t] = den; sf[t] = num;
    __syncthreads();
    for (int o = 128; o > 0; o >>= 1) {
        if (t < o) { su[t]+=su[t+o]; sv[t]+=sv[t+o]; sw[t]+=sw[t+o]; sf[t]+=sf[t+o]; }
        __syncthreads();
    }
    if (t == 0) {
        pcnt[blockIdx.x] = su[0]; pcle[blockIdx.x] = sv[0];
        pden7[blockIdx.x] = sw[0]; pnum7[blockIdx.x] = sf[0];
    }
}

// ---------------------------------------------------------------------------
// K3: decide + COMPLETE fallback hist path, one block. Skip path (always
// taken on this data): sum partials, write ohem_half, exit — ~1 µs.
// Hist path (general inputs): exact two-level radix select + reduce,
// serially in this block via global hist buffers. UNCHANGED from R15.
// ---------------------------------------------------------------------------
__global__ __launch_bounds__(256) void k_decide(const unsigned int* __restrict__ pcnt,
                                                const unsigned int* __restrict__ pcle,
                                                const unsigned int* __restrict__ pden7,
                                                const float*        __restrict__ pnum7,
                                                const float* __restrict__ pred,
                                                unsigned int* __restrict__ hist1,
                                                unsigned int* __restrict__ hist2,
                                                float* __restrict__ ohem_half)
{
    __shared__ unsigned int su[256], sv[256], sw[256];
    __shared__ float sf[256];
    __shared__ unsigned int meta[4];   // [skip, uidx, bucket, rank]
    __shared__ float sthr;
    const int t = threadIdx.x;

    su[t] = pcnt[t]; sv[t] = pcle[t]; sw[t] = pden7[t]; sf[t] = pnum7[t];
    __syncthreads();
    for (int o = 128; o > 0; o >>= 1) {
        if (t < o) { su[t]+=su[t+o]; sv[t]+=sv[t+o]; sw[t]+=sw[t+o]; sf[t]+=sf[t+o]; }
        __syncthreads();
    }
    if (t == 0) {
        const unsigned n_valid = su[0], cnt_le = sv[0];
        long long idx = (long long)n_valid - 1;
        if (idx > kMinKept) idx = kMinKept;
        if (idx < 0) idx = 0;
        const unsigned uidx = (unsigned)idx;
        const bool skip = (cnt_le >= uidx + 1);   // sorted[idx] <= 0.7 -> thr = 0.7
        meta[0] = skip ? 1u : 0u;
        meta[1] = uidx;
        if (skip) *ohem_half = 0.5f * (sf[0] / (float)sw[0]);
    }
    __syncthreads();
    if (meta[0]) return;                          // common case: done

    // ---------- fallback: exact threshold via two-level radix select ----------
    for (int j = t; j < H1_BINS + H2_BINS; j += 256)
        (j < H1_BINS ? hist1[j] : hist2[j - H1_BINS]) = 0u;
    __syncthreads();
    for (int i = t; i < kN; i += 256) {
        const unsigned bits = __float_as_uint(pred[i]);
        atomicAdd(&hist1[bits >> 16], 1u);
    }
    __syncthreads();
    {
        constexpr int PER = H1_BINS / 256;   // 128
        unsigned s = 0;
        for (int j = 0; j < PER; ++j) s += hist1[t * PER + j];
        su[t] = s;
        __syncthreads();
        if (t == 0) { unsigned acc = 0; for (int j = 0; j < 256; ++j) { sv[j] = acc; acc += su[j]; } }
        __syncthreads();
        const unsigned uidx = meta[1];
        if (uidx >= sv[t] && uidx < sv[t] + su[t]) {
            unsigned rank = uidx - sv[t];
            for (int j = 0; j < PER; ++j) {
                const unsigned c = hist1[t * PER + j];
                if (rank < c) { meta[2] = (unsigned)(t * PER + j); meta[3] = rank; break; }
                rank -= c;
            }
        }
    }
    __syncthreads();
    {
        const unsigned bucket = meta[2];
        for (int i = t; i < kN; i += 256) {
            const unsigned bits = __float_as_uint(pred[i]);
            if ((bits >> 16) == bucket) atomicAdd(&hist2[bits & 0xFFFFu], 1u);
        }
    }
    __syncthreads();
    {
        constexpr int PER = H2_BINS / 256;   // 256
        unsigned s = 0;
        for (int j = 0; j < PER; ++j) s += hist2[t * PER + j];
        su[t] = s;
        __syncthreads();
        if (t == 0) { unsigned acc = 0; for (int j = 0; j < 256; ++j) { sv[j] = acc; acc += su[j]; } }
        __syncthreads();
        const unsigned rank0 = meta[3];
        if (rank0 >= sv[t] && rank0 < sv[t] + su[t]) {
            unsigned rank = rank0 - sv[t];
            for (int j = 0; j < PER; ++j) {
                const unsigned c = hist2[t * PER + j];
                if (rank < c) {
                    const unsigned bits = (meta[2] << 16) | (unsigned)(t * PER + j);
                    sthr = fmaxf(__uint_as_float(bits), kThresh);
                    break;
                }
                rank -= c;
            }
        }
    }
    __syncthreads();
    {
        const float thrv = sthr;
        float num = 0.f; unsigned den = 0;
        for (int i4 = t; i4 < kN / 4; i4 += 256) {
            const float4 p4 = *(const float4*)(pred + i4 * 4);
            const float p[4] = {p4.x, p4.y, p4.z, p4.w};
            #pragma unroll
            for (int q = 0; q < 4; ++q)
                if (p[q] < thrv) { num += -__logf(p[q]); den += 1u; }
        }
        su[t] = den; sf[t] = num;
        __syncthreads();
        for (int o = 128; o > 0; o >>= 1) {
            if (t < o) { su[t]+=su[t+o]; sf[t]+=sf[t+o]; }
            __syncthreads();
        }
        if (t == 0) *ohem_half = 0.5f * (sf[0] / (float)su[0]);
    }
}

// ---------------------------------------------------------------------------
// K4: CE from score0 + broadcast OHEM add, fused — NONTEMPORAL score loads
// (same mechanical transform that won the R15 A/B on k_pred_b; body
// otherwise identical to the golden R11 kernel).
// ---------------------------------------------------------------------------
__global__ __launch_bounds__(256) void k_ce_out(const float* __restrict__ s0,
                                                const int* __restrict__ tgt,
                                                const float* __restrict__ ohem_half,
                                                float* __restrict__ out)
{
    const float oh = *ohem_half;   // uniform scalar
    const int i4 = blockIdx.x * blockDim.x + threadIdx.x;
    const int i  = i4 * 4;
    const int b  = i >> kHWShift;
    const int hw = i & (kHW - 1);
    const float* p0 = s0 + (size_t)b * kC * kHW + hw;

    f32x4 v[kC];
    #pragma unroll
    for (int c = 0; c < kC; ++c)
        v[c] = __builtin_nontemporal_load((const f32x4*)(p0 + (size_t)c * kHW));

    const int4 t4 = *(const int4*)(tgt + i);
    int tt[4] = {t4.x, t4.y, t4.z, t4.w};
    bool mk[4];
    #pragma unroll
    for (int q = 0; q < 4; ++q) {
        mk[q] = (tt[q] != kIgnore);
        tt[q] = mk[q] ? tt[q] : 0;
    }

    float sum[4] = {0.f, 0.f, 0.f, 0.f}, st[4] = {0.f, 0.f, 0.f, 0.f};
    #pragma unroll
    for (int c = 0; c < kC; ++c) {
        const float av[4] = {v[c][0], v[c][1], v[c][2], v[c][3]};
        #pragma unroll
        for (int q = 0; q < 4; ++q) {
            sum[q] += __expf(av[q]);
            st[q] = (c == tt[q]) ? av[q] : st[q];
        }
    }

    float4 o4;
    o4.x = (mk[0] ? 0.5f * (__logf(sum[0]) - st[0]) : 0.0f) + oh;
    o4.y = (mk[1] ? 0.5f * (__logf(sum[1]) - st[1]) : 0.0f) + oh;
    o4.z = (mk[2] ? 0.5f * (__logf(sum[2]) - st[2]) : 0.0f) + oh;
    o4.w = (mk[3] ? 0.5f * (__logf(sum[3]) - st[3]) : 0.0f) + oh;
    *(float4*)(out + i) = o4;
}

extern "C" void kernel_launch(void* const* d_in, const int* in_sizes, int n_in,
                              void* d_out, int out_size, void* d_ws, size_t ws_size,
                              hipStream_t stream)
{
    const float* s0  = (const float*)d_in[0];
    const float* s1  = (const float*)d_in[1];
    const int*   tgt = (const int*)d_in[2];
    float* out = (float*)d_out;

    // ws layout
    char* ws = (char*)d_ws;
    float* pred = (float*)ws;                              // kN f32 (8 MB)
    char*  A    = ws + (size_t)kN * 4;
    unsigned int* hist1 = (unsigned int*)A;                            // 128 KB
    unsigned int* hist2 = (unsigned int*)(A + (size_t)H1_BINS * 4);    // 256 KB
    float* ohem_half    = (float*)(A + (size_t)(H1_BINS + H2_BINS) * 4);
    unsigned int* pcnt  = (unsigned int*)(ohem_half + 1);  // 256 partials
    unsigned int* pcle  = pcnt + kCountBlocks;
    unsigned int* pden7 = pcle + kCountBlocks;
    float*        pnum7 = (float*)(pden7 + kCountBlocks);

    // No memset anywhere: all scratch plain-stored before read; hist buffers
    // are zeroed inside k_decide's fallback branch only.

    k_pred  <<<kN / 4 / 256, 256, 0, stream>>>(s1, tgt, pred);
    k_count <<<kCountBlocks, 256, 0, stream>>>(pred, pcnt, pcle, pden7, pnum7);
    k_decide<<<1, 256, 0, stream>>>(pcnt, pcle, pden7, pnum7, pred,
                                    hist1, hist2, ohem_half);
    k_ce_out<<<kN / 4 / 256, 256, 0, stream>>>(s0, tgt, ohem_half, out);
}